// Round 2
// baseline (163.193 us; speedup 1.0000x reference)
//
#include <hip/hip_runtime.h>

// FullyConnectedTP: e3nn-style fully-connected tensor product, MUL=16.
// out[n, j] for j<16       = PW0 * sum_u ( w1[n,u,j]*u0[u]*v0 + w4[n,u,j]*d4[u]*inv3 )
// out[n, 16+w*3+k]         = PW1 * sum_u ( w2[n,u,w]*u0[u]*v1[k]*inv3 + w3[n,u,w]*u1[u,k]*v0*inv3 )
// where d4[u] = dot(u1[u,:], v1), weight reshaped (N,4,16,16) row-major.
//
// One wave per edge, lane = output element. R2 change: weight block (4 KB)
// is staged to LDS with float4 coalesced loads (1 KB/vmem-instr instead of
// ~128 B/instr for the scalar column gather), column gather now hits LDS
// (<=2-way bank aliasing, free on CDNA4).

__global__ __launch_bounds__(256) void fctp_kernel(
    const float* __restrict__ u,
    const float* __restrict__ v,
    const float* __restrict__ wgt,
    float* __restrict__ out,
    int N)
{
    constexpr float INV_SQRT3 = 0.57735026918962576451f; // 1/sqrt(3)
    constexpr float PW0 = 0.17677669529663688110f;       // sqrt(1/32)
    constexpr float PW1 = 0.30618621784789726f;          // sqrt(3/32)

    const int lane = threadIdx.x & 63;
    const int wv   = threadIdx.x >> 6;      // wave within block (0..3)
    int n = blockIdx.x * 4 + wv;
    if (n >= N) n = N - 1;                  // benign, deterministic (N%4==0 anyway)

    __shared__ __align__(16) float shw[4][1024]; // per-wave weight tile (4 KB)
    __shared__ __align__(16) float shc[4][88];   // per-wave coefficients
    float* sw = shw[wv];
    float* sc = shc[wv];

    // ---- stage weight: 4 x global_load_dwordx4 per lane, fully coalesced ----
    const float4* wq = (const float4*)(wgt + (size_t)n * 1024);
    float4* wl = (float4*)sw;
#pragma unroll
    for (int t = 0; t < 4; ++t)
        wl[t * 64 + lane] = wq[t * 64 + lane];

    // ---- stage u row (coalesced) and v row (one dwordx4) ----
    sc[lane] = u[(size_t)n * 64 + lane];
    if (lane == 0)
        *(float4*)&sc[80] = ((const float4*)v)[n];
    __syncthreads();

    // ---- d4[u] = dot(u1[u,:], v1), lanes 0..15 ----
    if (lane < 16) {
        const int b = 16 + 3 * lane;
        sc[64 + lane] = sc[b] * sc[81] + sc[b + 1] * sc[82] + sc[b + 2] * sc[83];
    }
    __syncthreads();

    // ---- per-lane constants ----
    const bool is0 = (lane < 16);
    const int  o    = lane - 16;            // 0..47 for the l=1 outputs
    const int  wcol = is0 ? lane : (o / 3); // weight column this lane consumes
    const int  k    = is0 ? 0    : (o - 3 * wcol);
    const float v0  = sc[80];
    const float p   = is0 ? v0        : sc[81 + k] * INV_SQRT3;
    const float q   = is0 ? INV_SQRT3 : v0 * INV_SQRT3;
    // weight element offsets within the 1024-float block:
    //   w1 @ 0, w2 @ 256, w3 @ 512, w4 @ 768 ; element [u][col] at u*16+col
    const int offA = is0 ? wcol         : (256 + wcol); // w1 : w2
    const int offB = is0 ? (768 + wcol) : (512 + wcol); // w4 : w3
    const int offY  = is0 ? 64 : (16 + k);              // d4[u] vs u1[u][k]
    const int ystep = is0 ? 1 : 3;

    float acc = 0.0f;
#pragma unroll
    for (int uu = 0; uu < 16; ++uu) {
        const float X  = sc[uu];                 // u0[u] (broadcast)
        const float Y  = sc[offY + uu * ystep];  // d4[u] or u1[u][k]
        const float wa = sw[offA + uu * 16];     // LDS column gather
        const float wb = sw[offB + uu * 16];
        acc = fmaf(wa, X * p, acc);
        acc = fmaf(wb, Y * q, acc);
    }

    out[(size_t)n * 64 + lane] = (is0 ? PW0 : PW1) * acc;
}

extern "C" void kernel_launch(void* const* d_in, const int* in_sizes, int n_in,
                              void* d_out, int out_size, void* d_ws, size_t ws_size,
                              hipStream_t stream)
{
    const float* u   = (const float*)d_in[0];
    const float* v   = (const float*)d_in[1];
    const float* wgt = (const float*)d_in[2];
    float* out = (float*)d_out;

    const int N = in_sizes[1] / 4;      // v is (N,4)
    const int blocks = (N + 3) / 4;     // 4 edges (waves) per 256-thread block
    fctp_kernel<<<blocks, 256, 0, stream>>>(u, v, wgt, out, N);
}